// Round 1
// baseline (183.638 us; speedup 1.0000x reference)
//
#include <hip/hip_runtime.h>
#include <stdint.h>

#define ALPHA 1.702f
#define LIMIT 7.0f

typedef float f32x4 __attribute__((ext_vector_type(4)));
typedef __bf16 bf16x8 __attribute__((ext_vector_type(8)));

static __device__ __forceinline__ unsigned short f2bf(float f) {
    union { float f; uint32_t u; } v; v.f = f;
    uint32_t u = v.u;
    return (unsigned short)((u + 0x7FFFu + ((u >> 16) & 1u)) >> 16);
}

#define GLL16(GP, LP) __builtin_amdgcn_global_load_lds( \
    (const __attribute__((address_space(1))) void*)(GP), \
    (__attribute__((address_space(3))) void*)(LP), 16, 0, 0)

// ---------------------------------------------------------------------------
// Kernel 1: convert mlp1_w / mlp2_w fp32 -> bf16 (ws re-poisoned every launch)
// ---------------------------------------------------------------------------
__global__ __launch_bounds__(256) void convert_weights(
    const float* __restrict__ w1, const float* __restrict__ w2,
    unsigned short* __restrict__ w1b, unsigned short* __restrict__ w2b)
{
    const int idx = blockIdx.x * 256 + threadIdx.x;
    const int n1 = 4194304 / 4;  // 8*1024*512 / 4
    if (idx < n1) {
        float4 v = ((const float4*)w1)[idx];
        ushort4 r = { f2bf(v.x), f2bf(v.y), f2bf(v.z), f2bf(v.w) };
        ((ushort4*)w1b)[idx] = r;
    } else {
        const int i2 = idx - n1;  // < 524288
        float4 v = ((const float4*)w2)[i2];
        ushort4 r = { f2bf(v.x), f2bf(v.y), f2bf(v.z), f2bf(v.w) };
        ((ushort4*)w2b)[i2] = r;
    }
}

// ---------------------------------------------------------------------------
// Kernel 2: RMSNorm + bf16 t + gate logits(fp32) + softmax + top4 + coeff +
//           aux partial sums + out init (x + sum_e coeff*b2)
// grid 256 blocks x 256 thr; 1 wave = 2 tokens (serial)
// ---------------------------------------------------------------------------
__global__ __launch_bounds__(256) void gate_kernel(
    const float* __restrict__ x,
    const float* __restrict__ norm_scale,
    const float* __restrict__ gate_w,
    const float* __restrict__ gate_b,
    const float* __restrict__ b2,
    unsigned short* __restrict__ t_bf,
    float* __restrict__ coeff,
    float* __restrict__ accum,   // [48]: P_sum[8], imp[8], counts[4][8]
    float* __restrict__ out)
{
    __shared__ float red[4][48];
    const int wave = threadIdx.x >> 6;
    const int lane = threadIdx.x & 63;

    float accP[8], accI[8], accC[32];
    #pragma unroll
    for (int e = 0; e < 8; ++e) { accP[e] = 0.f; accI[e] = 0.f; }
    #pragma unroll
    for (int i = 0; i < 32; ++i) accC[i] = 0.f;

    #pragma unroll
    for (int it = 0; it < 2; ++it) {
        const int t = blockIdx.x * 8 + wave * 2 + it;
        const float4* xr = (const float4*)(x + t * 512);
        float4 x0 = xr[lane * 2];
        float4 x1 = xr[lane * 2 + 1];
        float ss = x0.x*x0.x + x0.y*x0.y + x0.z*x0.z + x0.w*x0.w
                 + x1.x*x1.x + x1.y*x1.y + x1.z*x1.z + x1.w*x1.w;
        #pragma unroll
        for (int off = 32; off > 0; off >>= 1) ss += __shfl_xor(ss, off, 64);
        const float rstd = rsqrtf(ss * (1.f / 512.f) + 1e-6f);
        const float4* sr = (const float4*)norm_scale;
        float4 s0 = sr[lane * 2], s1 = sr[lane * 2 + 1];
        float tv[8];
        tv[0] = x0.x * rstd * s0.x; tv[1] = x0.y * rstd * s0.y;
        tv[2] = x0.z * rstd * s0.z; tv[3] = x0.w * rstd * s0.w;
        tv[4] = x1.x * rstd * s1.x; tv[5] = x1.y * rstd * s1.y;
        tv[6] = x1.z * rstd * s1.z; tv[7] = x1.w * rstd * s1.w;
        // bf16 store of t (row-major [2048][512])
        uint32_t p0 = (uint32_t)f2bf(tv[0]) | ((uint32_t)f2bf(tv[1]) << 16);
        uint32_t p1 = (uint32_t)f2bf(tv[2]) | ((uint32_t)f2bf(tv[3]) << 16);
        uint32_t p2 = (uint32_t)f2bf(tv[4]) | ((uint32_t)f2bf(tv[5]) << 16);
        uint32_t p3 = (uint32_t)f2bf(tv[6]) | ((uint32_t)f2bf(tv[7]) << 16);
        uint4 pk; pk.x = p0; pk.y = p1; pk.z = p2; pk.w = p3;
        ((uint4*)(t_bf + t * 512))[lane] = pk;
        // gate logits from fp32 t (precision-critical for top-k)
        float le[8];
        #pragma unroll
        for (int e = 0; e < 8; ++e) {
            const float4* gw = (const float4*)(gate_w + e * 512);
            float4 g0 = gw[lane * 2], g1 = gw[lane * 2 + 1];
            float d = tv[0]*g0.x + tv[1]*g0.y + tv[2]*g0.z + tv[3]*g0.w
                    + tv[4]*g1.x + tv[5]*g1.y + tv[6]*g1.z + tv[7]*g1.w;
            #pragma unroll
            for (int off = 32; off > 0; off >>= 1) d += __shfl_xor(d, off, 64);
            le[e] = d + gate_b[e];
        }
        float mx = le[0];
        #pragma unroll
        for (int e = 1; e < 8; ++e) mx = fmaxf(mx, le[e]);
        float pe[8], se = 0.f;
        #pragma unroll
        for (int e = 0; e < 8; ++e) { pe[e] = __expf(le[e] - mx); se += pe[e]; }
        const float sinv = 1.f / se;
        #pragma unroll
        for (int e = 0; e < 8; ++e) pe[e] *= sinv;
        // top-4 (strict >, ascending scan keeps lowest index on ties)
        unsigned picked = 0;
        int ik[4]; float wk[4];
        #pragma unroll
        for (int k = 0; k < 4; ++k) {
            float bv = -1.f; int bi = 0;
            #pragma unroll
            for (int e = 0; e < 8; ++e)
                if (!(picked & (1u << e)) && pe[e] > bv) { bv = pe[e]; bi = e; }
            ik[k] = bi; wk[k] = bv; picked |= (1u << bi);
        }
        const float winv = 1.f / (wk[0] + wk[1] + wk[2] + wk[3]);
        float nw[4];
        #pragma unroll
        for (int k = 0; k < 4; ++k) nw[k] = wk[k] * winv;
        float ce[8];
        #pragma unroll
        for (int e = 0; e < 8; ++e) {
            float c = 0.f;
            #pragma unroll
            for (int k = 0; k < 4; ++k) c += (ik[k] == e) ? nw[k] : 0.f;
            ce[e] = c;
        }
        if (lane == 0) {
            #pragma unroll
            for (int e = 0; e < 8; ++e) coeff[t * 8 + e] = ce[e];
        }
        #pragma unroll
        for (int e = 0; e < 8; ++e) { accP[e] += pe[e]; accI[e] += le[e]; }
        #pragma unroll
        for (int k = 0; k < 4; ++k)
            #pragma unroll
            for (int e = 0; e < 8; ++e)
                accC[k * 8 + e] += (ik[k] == e) ? 1.f : 0.f;
        // out init: x + sum_e ce[e]*b2[e,:]
        float ov[8];
        ov[0] = x0.x; ov[1] = x0.y; ov[2] = x0.z; ov[3] = x0.w;
        ov[4] = x1.x; ov[5] = x1.y; ov[6] = x1.z; ov[7] = x1.w;
        #pragma unroll
        for (int e = 0; e < 8; ++e) {
            const float4* br = (const float4*)(b2 + e * 512);
            float4 b0 = br[lane * 2], bb1 = br[lane * 2 + 1];
            ov[0] += ce[e] * b0.x; ov[1] += ce[e] * b0.y;
            ov[2] += ce[e] * b0.z; ov[3] += ce[e] * b0.w;
            ov[4] += ce[e] * bb1.x; ov[5] += ce[e] * bb1.y;
            ov[6] += ce[e] * bb1.z; ov[7] += ce[e] * bb1.w;
        }
        float4 o0, o1;
        o0.x = ov[0]; o0.y = ov[1]; o0.z = ov[2]; o0.w = ov[3];
        o1.x = ov[4]; o1.y = ov[5]; o1.z = ov[6]; o1.w = ov[7];
        float4* orow = (float4*)(out + t * 512);
        orow[lane * 2] = o0; orow[lane * 2 + 1] = o1;
    }
    if (lane == 0) {
        #pragma unroll
        for (int e = 0; e < 8; ++e) { red[wave][e] = accP[e]; red[wave][8 + e] = accI[e]; }
        #pragma unroll
        for (int i = 0; i < 32; ++i) red[wave][16 + i] = accC[i];
    }
    __syncthreads();
    if (threadIdx.x < 48) {
        float s = red[0][threadIdx.x] + red[1][threadIdx.x]
                + red[2][threadIdx.x] + red[3][threadIdx.x];
        atomicAdd(accum + threadIdx.x, s);
    }
}

// ---------------------------------------------------------------------------
// Kernel 3: aux loss finalize (1 thread)
// ---------------------------------------------------------------------------
__global__ void aux_kernel(const float* __restrict__ accum, float* __restrict__ aux_out)
{
    if (threadIdx.x == 0 && blockIdx.x == 0) {
        float imp[8];
        float sl = 0.f;
        #pragma unroll
        for (int e = 0; e < 8; ++e) {
            float P = accum[e] * (1.f / 2048.f);
            imp[e] = accum[8 + e];
            float D = (16.f * accum[16 + e] + 8.f * accum[24 + e]
                     + 4.f * accum[32 + e] + 2.f * accum[40 + e]) * (1.f / 8192.f);
            sl += P * D;
        }
        float loss_load = 0.01f * 8.f * sl;
        float mean = 0.f;
        #pragma unroll
        for (int e = 0; e < 8; ++e) mean += imp[e];
        mean *= 0.125f;
        float var = 0.f;
        #pragma unroll
        for (int e = 0; e < 8; ++e) { float d = imp[e] - mean; var += d * d; }
        var *= (1.f / 7.f);
        float cv = sqrtf(var) / (mean + 1e-6f);
        *aux_out = loss_load + 0.01f * cv * cv;
    }
}

// ---------------------------------------------------------------------------
// Kernel 4: GEMM1 + swiglu*coeff epilogue.
// C[2048,8192] = t_bf[2048,512] @ w1b[8192,512]^T (+b1); As[t,e*512+j] =
// coeff[t,e]*swiglu(pair). 128x128 tiles, BK=32, 16x16x32 bf16 MFMA.
// ---------------------------------------------------------------------------
__global__ __launch_bounds__(256) void gemm1_swiglu(
    const unsigned short* __restrict__ A,   // [2048][512]
    const unsigned short* __restrict__ B,   // [8192][512]
    const float* __restrict__ b1,           // [8192]
    const float* __restrict__ coeff,        // [2048][8]
    unsigned short* __restrict__ As)        // [2048][4096]
{
    __shared__ unsigned short tA[128 * 32];
    __shared__ unsigned short tB[128 * 32];
    const int tid = threadIdx.x;
    const int bx = blockIdx.x;
    const int tile_n = bx & 63, tile_m = bx >> 6;
    const int m0 = tile_m * 128, n0 = tile_n * 128;
    const int lane = tid & 63, wave = tid >> 6;
    const int wm = (wave & 1) * 64, wn = (wave >> 1) * 64;
    const int quad = lane >> 4, l16 = lane & 15;

    f32x4 acc[4][4];
    #pragma unroll
    for (int i = 0; i < 4; ++i)
        #pragma unroll
        for (int j = 0; j < 4; ++j) { f32x4 z = {0.f, 0.f, 0.f, 0.f}; acc[i][j] = z; }

    const int j0 = tid, j1 = tid + 256;
    const int ar0 = j0 >> 2, ak0 = (j0 & 3) * 8;
    const int ar1 = j1 >> 2, ak1 = (j1 & 3) * 8;

    for (int k0 = 0; k0 < 512; k0 += 32) {
        GLL16(A + (m0 + ar0) * 512 + k0 + ak0, tA + j0 * 8);
        GLL16(A + (m0 + ar1) * 512 + k0 + ak1, tA + j1 * 8);
        GLL16(B + (n0 + ar0) * 512 + k0 + ak0, tB + j0 * 8);
        GLL16(B + (n0 + ar1) * 512 + k0 + ak1, tB + j1 * 8);
        __syncthreads();
        bf16x8 af[4], bfr[4];
        #pragma unroll
        for (int i = 0; i < 4; ++i) {
            af[i]  = *(const bf16x8*)(tA + (wm + i * 16 + l16) * 32 + quad * 8);
            bfr[i] = *(const bf16x8*)(tB + (wn + i * 16 + l16) * 32 + quad * 8);
        }
        #pragma unroll
        for (int i = 0; i < 4; ++i)
            #pragma unroll
            for (int j = 0; j < 4; ++j)
                acc[i][j] = __builtin_amdgcn_mfma_f32_16x16x32_bf16(af[i], bfr[j], acc[i][j], 0, 0, 0);
        __syncthreads();
    }

    const int e = n0 >> 10;  // 128-col tile never straddles an expert (1024 cols)
    #pragma unroll
    for (int j = 0; j < 4; ++j) {
        const int col = n0 + wn + j * 16 + l16;
        const float bias = b1[col];
        #pragma unroll
        for (int i = 0; i < 4; ++i) {
            const int rowb = m0 + wm + i * 16 + quad * 4;
            #pragma unroll
            for (int r = 0; r < 4; ++r) {
                const int row = rowb + r;
                float v = acc[i][j][r] + bias;
                v = fminf(fmaxf(v, -LIMIT), LIMIT);
                float partner = __shfl_xor(v, 1, 64);
                if ((lane & 1) == 0) {  // even col: glu=self, lin=partner
                    float g = v;
                    float aval = g / (1.f + __expf(-ALPHA * g)) + partner + 1.f;
                    aval *= coeff[row * 8 + e];
                    As[row * 4096 + (col >> 1)] = f2bf(aval);
                }
            }
        }
    }
}

// ---------------------------------------------------------------------------
// Kernel 5: GEMM2 split-K=4 with fp32 atomicAdd into pre-initialized out.
// out[t,h] += sum_{k=e*512+i} As[t,k] * w2b[e,h,i]
// ---------------------------------------------------------------------------
__global__ __launch_bounds__(256) void gemm2(
    const unsigned short* __restrict__ As,  // [2048][4096]
    const unsigned short* __restrict__ w2,  // [8][512][512] (e,h,i) bf16
    float* __restrict__ out)                // [2048][512]
{
    __shared__ unsigned short tA[128 * 32];
    __shared__ unsigned short tB[128 * 32];
    const int tid = threadIdx.x;
    const int bx = blockIdx.x;              // 256 = 4(n) * 16(m) * 4(sk)
    const int tile_n = bx & 3;
    const int tile_m = (bx >> 2) & 15;
    const int sk = bx >> 6;
    const int m0 = tile_m * 128, n0 = tile_n * 128, kbase = sk * 1024;
    const int lane = tid & 63, wave = tid >> 6;
    const int wm = (wave & 1) * 64, wn = (wave >> 1) * 64;
    const int quad = lane >> 4, l16 = lane & 15;

    f32x4 acc[4][4];
    #pragma unroll
    for (int i = 0; i < 4; ++i)
        #pragma unroll
        for (int j = 0; j < 4; ++j) { f32x4 z = {0.f, 0.f, 0.f, 0.f}; acc[i][j] = z; }

    const int j0 = tid, j1 = tid + 256;
    const int ar0 = j0 >> 2, ak0 = (j0 & 3) * 8;
    const int ar1 = j1 >> 2, ak1 = (j1 & 3) * 8;

    for (int kt = 0; kt < 32; ++kt) {
        const int k0 = kbase + kt * 32;
        const int kk0 = k0 + ak0, kk1 = k0 + ak1;
        GLL16(As + (m0 + ar0) * 4096 + kk0, tA + j0 * 8);
        GLL16(As + (m0 + ar1) * 4096 + kk1, tA + j1 * 8);
        // B row n=h, k=e*512+i -> addr e*262144 + h*512 + i
        GLL16(w2 + (kk0 >> 9) * 262144 + (n0 + ar0) * 512 + (kk0 & 511), tB + j0 * 8);
        GLL16(w2 + (kk1 >> 9) * 262144 + (n0 + ar1) * 512 + (kk1 & 511), tB + j1 * 8);
        __syncthreads();
        bf16x8 af[4], bfr[4];
        #pragma unroll
        for (int i = 0; i < 4; ++i) {
            af[i]  = *(const bf16x8*)(tA + (wm + i * 16 + l16) * 32 + quad * 8);
            bfr[i] = *(const bf16x8*)(tB + (wn + i * 16 + l16) * 32 + quad * 8);
        }
        #pragma unroll
        for (int i = 0; i < 4; ++i)
            #pragma unroll
            for (int j = 0; j < 4; ++j)
                acc[i][j] = __builtin_amdgcn_mfma_f32_16x16x32_bf16(af[i], bfr[j], acc[i][j], 0, 0, 0);
        __syncthreads();
    }

    #pragma unroll
    for (int j = 0; j < 4; ++j) {
        const int col = n0 + wn + j * 16 + l16;
        #pragma unroll
        for (int i = 0; i < 4; ++i) {
            const int rowb = m0 + wm + i * 16 + quad * 4;
            #pragma unroll
            for (int r = 0; r < 4; ++r)
                atomicAdd(&out[(rowb + r) * 512 + col], acc[i][j][r]);
        }
    }
}

// ---------------------------------------------------------------------------
extern "C" void kernel_launch(void* const* d_in, const int* in_sizes, int n_in,
                              void* d_out, int out_size, void* d_ws, size_t ws_size,
                              hipStream_t stream)
{
    (void)in_sizes; (void)n_in; (void)out_size; (void)ws_size;
    const float* x          = (const float*)d_in[0];
    const float* norm_scale = (const float*)d_in[1];
    const float* gate_w     = (const float*)d_in[2];
    const float* gate_b     = (const float*)d_in[3];
    const float* mlp1_w     = (const float*)d_in[4];
    const float* mlp1_b     = (const float*)d_in[5];
    const float* mlp2_w     = (const float*)d_in[6];
    const float* mlp2_b     = (const float*)d_in[7];
    float* out = (float*)d_out;

    char* ws = (char*)d_ws;
    unsigned short* w1b   = (unsigned short*)(ws);              // 8,388,608 B
    unsigned short* w2b   = (unsigned short*)(ws + 8388608);    // 4,194,304 B
    unsigned short* tbf   = (unsigned short*)(ws + 12582912);   // 2,097,152 B
    unsigned short* As    = (unsigned short*)(ws + 14680064);   // 16,777,216 B
    float*          coeff = (float*)(ws + 31457280);            // 65,536 B
    float*          accum = (float*)(ws + 31522816);            // 192 B

    hipMemsetAsync(accum, 0, 48 * sizeof(float), stream);
    convert_weights<<<6144, 256, 0, stream>>>(mlp1_w, mlp2_w, w1b, w2b);
    gate_kernel<<<256, 256, 0, stream>>>(x, norm_scale, gate_w, gate_b, mlp2_b,
                                         tbf, coeff, accum, out);
    aux_kernel<<<1, 64, 0, stream>>>(accum, out + 2048 * 512);
    gemm1_swiglu<<<1024, 256, 0, stream>>>(tbf, w1b, mlp1_b, coeff, As);
    gemm2<<<256, 256, 0, stream>>>(As, w2b, out);
}

// Round 2
// 168.289 us; speedup vs baseline: 1.0912x; 1.0912x over previous
//
#include <hip/hip_runtime.h>
#include <stdint.h>

#define ALPHA 1.702f
#define LIMIT 7.0f

typedef float f32x4 __attribute__((ext_vector_type(4)));
typedef __bf16 bf16x8 __attribute__((ext_vector_type(8)));

static __device__ __forceinline__ unsigned short f2bf(float f) {
    union { float f; uint32_t u; } v; v.f = f;
    uint32_t u = v.u;
    return (unsigned short)((u + 0x7FFFu + ((u >> 16) & 1u)) >> 16);
}

#define GLL16(GP, LP) __builtin_amdgcn_global_load_lds( \
    (const __attribute__((address_space(1))) void*)(GP), \
    (__attribute__((address_space(3))) void*)(LP), 16, 0, 0)

// ---------------------------------------------------------------------------
// prep: blocks [0,6144): fp32->bf16 weight convert, with W1 permuted into
//       glu-half/lin-half per expert (w1p[e][c][:]=w1[e][2c][:],
//       w1p[e][512+c][:]=w1[e][2c+1][:]).
//       blocks [6144,6400): gate (RMSNorm + bf16 t + fp32 logits + top4 +
//       coeff + aux partials + out init x + sum_e coeff*b2).
// ---------------------------------------------------------------------------
__global__ __launch_bounds__(256) void prep_kernel(
    const float* __restrict__ w1, const float* __restrict__ w2,
    unsigned short* __restrict__ w1p, unsigned short* __restrict__ w2b,
    const float* __restrict__ x,
    const float* __restrict__ norm_scale,
    const float* __restrict__ gate_w,
    const float* __restrict__ gate_b,
    const float* __restrict__ b2,
    unsigned short* __restrict__ t_bf,
    float* __restrict__ coeff,
    float* __restrict__ accum,
    float* __restrict__ out)
{
    __shared__ float red[4][48];
    if (blockIdx.x < 6144) {
        const int idx = blockIdx.x * 256 + threadIdx.x;
        const int n1 = 1048576;  // 8*1024*512/4 float4s of w1
        if (idx < n1) {
            const int e = idx >> 17;        // 131072 float4 per expert
            const int rem = idx & 131071;
            const int r = rem >> 7;         // dest row in [0,1024)
            const int c = rem & 127;
            const int src = (r < 512) ? (2 * r) : (2 * (r - 512) + 1);
            float4 v = ((const float4*)w1)[(e << 17) + (src << 7) + c];
            ushort4 o = { f2bf(v.x), f2bf(v.y), f2bf(v.z), f2bf(v.w) };
            ((ushort4*)w1p)[idx] = o;
        } else {
            const int i2 = idx - n1;        // < 524288
            float4 v = ((const float4*)w2)[i2];
            ushort4 o = { f2bf(v.x), f2bf(v.y), f2bf(v.z), f2bf(v.w) };
            ((ushort4*)w2b)[i2] = o;
        }
        return;
    }
    // ---- gate part ----
    const int bid = blockIdx.x - 6144;
    const int wave = threadIdx.x >> 6;
    const int lane = threadIdx.x & 63;

    float accP[8], accI[8], accC[32];
    #pragma unroll
    for (int e = 0; e < 8; ++e) { accP[e] = 0.f; accI[e] = 0.f; }
    #pragma unroll
    for (int i = 0; i < 32; ++i) accC[i] = 0.f;

    #pragma unroll
    for (int it = 0; it < 2; ++it) {
        const int t = bid * 8 + wave * 2 + it;
        const float4* xr = (const float4*)(x + t * 512);
        float4 x0 = xr[lane * 2];
        float4 x1 = xr[lane * 2 + 1];
        float ss = x0.x*x0.x + x0.y*x0.y + x0.z*x0.z + x0.w*x0.w
                 + x1.x*x1.x + x1.y*x1.y + x1.z*x1.z + x1.w*x1.w;
        #pragma unroll
        for (int off = 32; off > 0; off >>= 1) ss += __shfl_xor(ss, off, 64);
        const float rstd = rsqrtf(ss * (1.f / 512.f) + 1e-6f);
        const float4* sr = (const float4*)norm_scale;
        float4 s0 = sr[lane * 2], s1 = sr[lane * 2 + 1];
        float tv[8];
        tv[0] = x0.x * rstd * s0.x; tv[1] = x0.y * rstd * s0.y;
        tv[2] = x0.z * rstd * s0.z; tv[3] = x0.w * rstd * s0.w;
        tv[4] = x1.x * rstd * s1.x; tv[5] = x1.y * rstd * s1.y;
        tv[6] = x1.z * rstd * s1.z; tv[7] = x1.w * rstd * s1.w;
        uint32_t p0 = (uint32_t)f2bf(tv[0]) | ((uint32_t)f2bf(tv[1]) << 16);
        uint32_t p1 = (uint32_t)f2bf(tv[2]) | ((uint32_t)f2bf(tv[3]) << 16);
        uint32_t p2 = (uint32_t)f2bf(tv[4]) | ((uint32_t)f2bf(tv[5]) << 16);
        uint32_t p3 = (uint32_t)f2bf(tv[6]) | ((uint32_t)f2bf(tv[7]) << 16);
        uint4 pk; pk.x = p0; pk.y = p1; pk.z = p2; pk.w = p3;
        ((uint4*)(t_bf + t * 512))[lane] = pk;
        float le[8];
        #pragma unroll
        for (int e = 0; e < 8; ++e) {
            const float4* gw = (const float4*)(gate_w + e * 512);
            float4 g0 = gw[lane * 2], g1 = gw[lane * 2 + 1];
            float d = tv[0]*g0.x + tv[1]*g0.y + tv[2]*g0.z + tv[3]*g0.w
                    + tv[4]*g1.x + tv[5]*g1.y + tv[6]*g1.z + tv[7]*g1.w;
            #pragma unroll
            for (int off = 32; off > 0; off >>= 1) d += __shfl_xor(d, off, 64);
            le[e] = d + gate_b[e];
        }
        float mx = le[0];
        #pragma unroll
        for (int e = 1; e < 8; ++e) mx = fmaxf(mx, le[e]);
        float pe[8], se = 0.f;
        #pragma unroll
        for (int e = 0; e < 8; ++e) { pe[e] = __expf(le[e] - mx); se += pe[e]; }
        const float sinv = 1.f / se;
        #pragma unroll
        for (int e = 0; e < 8; ++e) pe[e] *= sinv;
        unsigned picked = 0;
        int ik[4]; float wk[4];
        #pragma unroll
        for (int k = 0; k < 4; ++k) {
            float bv = -1.f; int bi = 0;
            #pragma unroll
            for (int e = 0; e < 8; ++e)
                if (!(picked & (1u << e)) && pe[e] > bv) { bv = pe[e]; bi = e; }
            ik[k] = bi; wk[k] = bv; picked |= (1u << bi);
        }
        const float winv = 1.f / (wk[0] + wk[1] + wk[2] + wk[3]);
        float nw[4];
        #pragma unroll
        for (int k = 0; k < 4; ++k) nw[k] = wk[k] * winv;
        float ce[8];
        #pragma unroll
        for (int e = 0; e < 8; ++e) {
            float c = 0.f;
            #pragma unroll
            for (int k = 0; k < 4; ++k) c += (ik[k] == e) ? nw[k] : 0.f;
            ce[e] = c;
        }
        if (lane == 0) {
            #pragma unroll
            for (int e = 0; e < 8; ++e) coeff[t * 8 + e] = ce[e];
        }
        #pragma unroll
        for (int e = 0; e < 8; ++e) { accP[e] += pe[e]; accI[e] += le[e]; }
        #pragma unroll
        for (int k = 0; k < 4; ++k)
            #pragma unroll
            for (int e = 0; e < 8; ++e)
                accC[k * 8 + e] += (ik[k] == e) ? 1.f : 0.f;
        float ov[8];
        ov[0] = x0.x; ov[1] = x0.y; ov[2] = x0.z; ov[3] = x0.w;
        ov[4] = x1.x; ov[5] = x1.y; ov[6] = x1.z; ov[7] = x1.w;
        #pragma unroll
        for (int e = 0; e < 8; ++e) {
            const float4* br = (const float4*)(b2 + e * 512);
            float4 b0 = br[lane * 2], bb1 = br[lane * 2 + 1];
            ov[0] += ce[e] * b0.x; ov[1] += ce[e] * b0.y;
            ov[2] += ce[e] * b0.z; ov[3] += ce[e] * b0.w;
            ov[4] += ce[e] * bb1.x; ov[5] += ce[e] * bb1.y;
            ov[6] += ce[e] * bb1.z; ov[7] += ce[e] * bb1.w;
        }
        float4 o0, o1;
        o0.x = ov[0]; o0.y = ov[1]; o0.z = ov[2]; o0.w = ov[3];
        o1.x = ov[4]; o1.y = ov[5]; o1.z = ov[6]; o1.w = ov[7];
        float4* orow = (float4*)(out + t * 512);
        orow[lane * 2] = o0; orow[lane * 2 + 1] = o1;
    }
    if (lane == 0) {
        #pragma unroll
        for (int e = 0; e < 8; ++e) { red[wave][e] = accP[e]; red[wave][8 + e] = accI[e]; }
        #pragma unroll
        for (int i = 0; i < 32; ++i) red[wave][16 + i] = accC[i];
    }
    __syncthreads();
    if (threadIdx.x < 48) {
        float s = red[0][threadIdx.x] + red[1][threadIdx.x]
                + red[2][threadIdx.x] + red[3][threadIdx.x];
        atomicAdd(accum + threadIdx.x, s);
    }
}

// ---------------------------------------------------------------------------
// aux loss finalize
// ---------------------------------------------------------------------------
__global__ void aux_kernel(const float* __restrict__ accum, float* __restrict__ aux_out)
{
    if (threadIdx.x == 0 && blockIdx.x == 0) {
        float imp[8];
        float sl = 0.f;
        #pragma unroll
        for (int e = 0; e < 8; ++e) {
            float P = accum[e] * (1.f / 2048.f);
            imp[e] = accum[8 + e];
            float D = (16.f * accum[16 + e] + 8.f * accum[24 + e]
                     + 4.f * accum[32 + e] + 2.f * accum[40 + e]) * (1.f / 8192.f);
            sl += P * D;
        }
        float loss_load = 0.01f * 8.f * sl;
        float mean = 0.f;
        #pragma unroll
        for (int e = 0; e < 8; ++e) mean += imp[e];
        mean *= 0.125f;
        float var = 0.f;
        #pragma unroll
        for (int e = 0; e < 8; ++e) { float d = imp[e] - mean; var += d * d; }
        var *= (1.f / 7.f);
        float cv = sqrtf(var) / (mean + 1e-6f);
        *aux_out = loss_load + 0.01f * cv * cv;
    }
}

// ---------------------------------------------------------------------------
// GEMM1 + swiglu*coeff. Per block: 128 rows x 128 As-cols. Stages A-tile +
// glu B-tile + lin B-tile (w1p is glu/lin split), two accumulator sets,
// no shfl in epilogue, all 64 lanes store.
// grid 512 = 16 m-tiles x 32 As-col tiles.
// ---------------------------------------------------------------------------
__global__ __launch_bounds__(256, 2) void gemm1_swiglu(
    const unsigned short* __restrict__ A,    // t_bf [2048][512]
    const unsigned short* __restrict__ w1p,  // [8][1024][512] glu/lin split
    const float* __restrict__ b1,            // [8][1024] original interleaved
    const float* __restrict__ coeff,         // [2048][8]
    unsigned short* __restrict__ As)         // [2048][4096]
{
    __shared__ unsigned short tA[128 * 32];
    __shared__ unsigned short tBg[128 * 32];
    __shared__ unsigned short tBl[128 * 32];
    const int tid = threadIdx.x;
    const int bx = blockIdx.x;
    const int tile_p = bx & 31, tile_m = bx >> 5;
    const int e = tile_p >> 2;
    const int np = (tile_p & 3) * 128;       // col offset within expert [0,512)
    const int m0 = tile_m * 128;
    const int lane = tid & 63, wave = tid >> 6;
    const int wm = (wave & 1) * 64, wn = (wave >> 1) * 64;
    const int quad = lane >> 4, l16 = lane & 15;

    f32x4 accG[4][4], accL[4][4];
    #pragma unroll
    for (int i = 0; i < 4; ++i)
        #pragma unroll
        for (int j = 0; j < 4; ++j) {
            f32x4 z = {0.f, 0.f, 0.f, 0.f};
            accG[i][j] = z; accL[i][j] = z;
        }

    const int j0 = tid, j1 = tid + 256;
    const int ar0 = j0 >> 2, ak0 = (j0 & 3) * 8;
    const int ar1 = j1 >> 2, ak1 = (j1 & 3) * 8;

    const unsigned short* Bg = w1p + (e * 1024 + np) * 512;
    const unsigned short* Bl = Bg + 512 * 512;

    for (int k0 = 0; k0 < 512; k0 += 32) {
        GLL16(A + (m0 + ar0) * 512 + k0 + ak0, tA + j0 * 8);
        GLL16(A + (m0 + ar1) * 512 + k0 + ak1, tA + j1 * 8);
        GLL16(Bg + ar0 * 512 + k0 + ak0, tBg + j0 * 8);
        GLL16(Bg + ar1 * 512 + k0 + ak1, tBg + j1 * 8);
        GLL16(Bl + ar0 * 512 + k0 + ak0, tBl + j0 * 8);
        GLL16(Bl + ar1 * 512 + k0 + ak1, tBl + j1 * 8);
        __syncthreads();
        bf16x8 af[4], bg[4], bl[4];
        #pragma unroll
        for (int i = 0; i < 4; ++i) {
            af[i] = *(const bf16x8*)(tA  + (wm + i * 16 + l16) * 32 + quad * 8);
            bg[i] = *(const bf16x8*)(tBg + (wn + i * 16 + l16) * 32 + quad * 8);
            bl[i] = *(const bf16x8*)(tBl + (wn + i * 16 + l16) * 32 + quad * 8);
        }
        #pragma unroll
        for (int i = 0; i < 4; ++i)
            #pragma unroll
            for (int j = 0; j < 4; ++j) {
                accG[i][j] = __builtin_amdgcn_mfma_f32_16x16x32_bf16(af[i], bg[j], accG[i][j], 0, 0, 0);
                accL[i][j] = __builtin_amdgcn_mfma_f32_16x16x32_bf16(af[i], bl[j], accL[i][j], 0, 0, 0);
            }
        __syncthreads();
    }

    // coeff for the 16 rows this lane owns
    float cw[4][4];
    #pragma unroll
    for (int i = 0; i < 4; ++i) {
        const int rowb = m0 + wm + i * 16 + quad * 4;
        #pragma unroll
        for (int r = 0; r < 4; ++r) cw[i][r] = coeff[(rowb + r) * 8 + e];
    }
    #pragma unroll
    for (int j = 0; j < 4; ++j) {
        const int colp = np + wn + j * 16 + l16;   // [0,512) within expert
        const float bgv = b1[e * 1024 + 2 * colp];
        const float blv = b1[e * 1024 + 2 * colp + 1];
        #pragma unroll
        for (int i = 0; i < 4; ++i) {
            const int rowb = m0 + wm + i * 16 + quad * 4;
            #pragma unroll
            for (int r = 0; r < 4; ++r) {
                float g = fminf(fmaxf(accG[i][j][r] + bgv, -LIMIT), LIMIT);
                float l = fminf(fmaxf(accL[i][j][r] + blv, -LIMIT), LIMIT);
                float a = g / (1.f + __expf(-ALPHA * g)) + l + 1.f;
                a *= cw[i][r];
                As[(rowb + r) * 4096 + e * 512 + colp] = f2bf(a);
            }
        }
    }
}

// ---------------------------------------------------------------------------
// GEMM2 split-K=8 (one expert per K-slice), fp32 atomicAdd into out.
// grid 512 = 4 n-tiles x 16 m-tiles x 8 sk. 16 K-iters each.
// ---------------------------------------------------------------------------
__global__ __launch_bounds__(256) void gemm2(
    const unsigned short* __restrict__ As,  // [2048][4096]
    const unsigned short* __restrict__ w2,  // [8][512][512] bf16
    float* __restrict__ out)                // [2048][512]
{
    __shared__ unsigned short tA[128 * 32];
    __shared__ unsigned short tB[128 * 32];
    const int tid = threadIdx.x;
    const int bx = blockIdx.x;
    const int tile_n = bx & 3;
    const int tile_m = (bx >> 2) & 15;
    const int e = bx >> 6;                   // sk == expert
    const int m0 = tile_m * 128, n0 = tile_n * 128;
    const int lane = tid & 63, wave = tid >> 6;
    const int wm = (wave & 1) * 64, wn = (wave >> 1) * 64;
    const int quad = lane >> 4, l16 = lane & 15;

    f32x4 acc[4][4];
    #pragma unroll
    for (int i = 0; i < 4; ++i)
        #pragma unroll
        for (int j = 0; j < 4; ++j) { f32x4 z = {0.f, 0.f, 0.f, 0.f}; acc[i][j] = z; }

    const int j0 = tid, j1 = tid + 256;
    const int ar0 = j0 >> 2, ak0 = (j0 & 3) * 8;
    const int ar1 = j1 >> 2, ak1 = (j1 & 3) * 8;

    const unsigned short* Asl = As + e * 512;              // this expert's K block
    const unsigned short* Bb  = w2 + e * 262144;           // [512][512]

    for (int kt = 0; kt < 16; ++kt) {
        const int k0 = kt * 32;
        GLL16(Asl + (m0 + ar0) * 4096 + k0 + ak0, tA + j0 * 8);
        GLL16(Asl + (m0 + ar1) * 4096 + k0 + ak1, tA + j1 * 8);
        GLL16(Bb + (n0 + ar0) * 512 + k0 + ak0, tB + j0 * 8);
        GLL16(Bb + (n0 + ar1) * 512 + k0 + ak1, tB + j1 * 8);
        __syncthreads();
        bf16x8 af[4], bfr[4];
        #pragma unroll
        for (int i = 0; i < 4; ++i) {
            af[i]  = *(const bf16x8*)(tA + (wm + i * 16 + l16) * 32 + quad * 8);
            bfr[i] = *(const bf16x8*)(tB + (wn + i * 16 + l16) * 32 + quad * 8);
        }
        #pragma unroll
        for (int i = 0; i < 4; ++i)
            #pragma unroll
            for (int j = 0; j < 4; ++j)
                acc[i][j] = __builtin_amdgcn_mfma_f32_16x16x32_bf16(af[i], bfr[j], acc[i][j], 0, 0, 0);
        __syncthreads();
    }

    #pragma unroll
    for (int j = 0; j < 4; ++j) {
        const int col = n0 + wn + j * 16 + l16;
        #pragma unroll
        for (int i = 0; i < 4; ++i) {
            const int rowb = m0 + wm + i * 16 + quad * 4;
            #pragma unroll
            for (int r = 0; r < 4; ++r)
                atomicAdd(&out[(rowb + r) * 512 + col], acc[i][j][r]);
        }
    }
}

// ---------------------------------------------------------------------------
extern "C" void kernel_launch(void* const* d_in, const int* in_sizes, int n_in,
                              void* d_out, int out_size, void* d_ws, size_t ws_size,
                              hipStream_t stream)
{
    (void)in_sizes; (void)n_in; (void)out_size; (void)ws_size;
    const float* x          = (const float*)d_in[0];
    const float* norm_scale = (const float*)d_in[1];
    const float* gate_w     = (const float*)d_in[2];
    const float* gate_b     = (const float*)d_in[3];
    const float* mlp1_w     = (const float*)d_in[4];
    const float* mlp1_b     = (const float*)d_in[5];
    const float* mlp2_w     = (const float*)d_in[6];
    const float* mlp2_b     = (const float*)d_in[7];
    float* out = (float*)d_out;

    char* ws = (char*)d_ws;
    unsigned short* w1p   = (unsigned short*)(ws);              // 8,388,608 B
    unsigned short* w2b   = (unsigned short*)(ws + 8388608);    // 4,194,304 B
    unsigned short* tbf   = (unsigned short*)(ws + 12582912);   // 2,097,152 B
    unsigned short* As    = (unsigned short*)(ws + 14680064);   // 16,777,216 B
    float*          coeff = (float*)(ws + 31457280);            // 65,536 B
    float*          accum = (float*)(ws + 31522816);            // 192 B

    hipMemsetAsync(accum, 0, 48 * sizeof(float), stream);
    prep_kernel<<<6400, 256, 0, stream>>>(mlp1_w, mlp2_w, w1p, w2b,
                                          x, norm_scale, gate_w, gate_b, mlp2_b,
                                          tbf, coeff, accum, out);
    aux_kernel<<<1, 64, 0, stream>>>(accum, out + 2048 * 512);
    gemm1_swiglu<<<512, 256, 0, stream>>>(tbf, w1p, mlp1_b, coeff, As);
    gemm2<<<512, 256, 0, stream>>>(As, w2b, out);
}